// Round 4
// baseline (602.491 us; speedup 1.0000x reference)
//
#include <hip/hip_runtime.h>

// Problem constants
#define Bsz 16
#define Dch 1024
#define Tsz 1024
#define Hsz 1024
#define Mtot (Bsz*Tsz)   // 16384
#define K2   (2*Dch)     // 2048
#define Ntot (3*Hsz)     // 3072
#define NCH  32          // scan chunks per chain
#define CL   32          // chunk length (NCH*CL == Tsz)
#define NSEQ 32          // 16 b * 2 hb independent scan sequences

typedef __attribute__((ext_vector_type(8))) short bf16x8;
typedef __attribute__((ext_vector_type(4))) float f32x4;

__device__ __forceinline__ unsigned short f2bf(float x) {
    unsigned u = __float_as_uint(x);
    u += 0x7FFFu + ((u >> 16) & 1u);   // round-to-nearest-even
    return (unsigned short)(u >> 16);
}
__device__ __forceinline__ unsigned short f2h(float x) {
    _Float16 h = (_Float16)x;
    return __builtin_bit_cast(unsigned short, h);
}
__device__ __forceinline__ float h2f(unsigned short u) {
    _Float16 h = __builtin_bit_cast(_Float16, u);
    return (float)h;
}

// async global->LDS, 16B per lane, dest = ldsbase + lane*16 (wave-uniform base)
#define GLOAD_LDS16(gp, lp) \
    __builtin_amdgcn_global_load_lds((const __attribute__((address_space(1))) void*)(gp), \
                                     (__attribute__((address_space(3))) void*)(lp), 16, 0, 0)

// Merged prep: blocks [0,4096) build A2 (LDS transpose + causal shift + bf16 pack);
// blocks [4096,5632) cast conv_w fp32->bf16 (flat layout IS B^T row-major already).
__global__ __launch_bounds__(256)
void prep(const float* __restrict__ x, unsigned short* __restrict__ a2,
          const float* __restrict__ w, unsigned short* __restrict__ wb) {
    __shared__ float Xs[64][66];
    int bid = blockIdx.x;
    int tid = threadIdx.x;
    if (bid >= 4096) {
        int i0 = (bid - 4096) * 256 + tid;
        #pragma unroll
        for (int k = 0; k < 4; k++) {
            int i = i0 + k * (1536 * 256);
            float4 v = ((const float4*)w)[i];
            ushort4 r;
            r.x = f2bf(v.x); r.y = f2bf(v.y); r.z = f2bf(v.z); r.w = f2bf(v.w);
            ((ushort4*)wb)[i] = r;
        }
        return;
    }
    int b   = bid >> 8;
    int tt0 = ((bid >> 4) & 15) << 6;
    int dd0 = (bid & 15) << 6;
    int colt = tid & 63, rowq = tid >> 6;
    const size_t xbase = (size_t)b * (Dch * Tsz);
    #pragma unroll
    for (int r = 0; r < 16; r++) {
        int dd = r * 4 + rowq;
        Xs[dd][1 + colt] = x[xbase + (size_t)(dd0 + dd) * Tsz + tt0 + colt];
    }
    if (tid < 64) {
        Xs[tid][0] = (tt0 == 0) ? 0.f : x[xbase + (size_t)(dd0 + tid) * Tsz + tt0 - 1];
    }
    __syncthreads();
    #pragma unroll
    for (int r = 0; r < 16; r++) {
        int tr = r * 4 + rowq;
        int dc = colt;
        float v0 = Xs[dc][tr];       // x[t-1]
        float v1 = Xs[dc][tr + 1];   // x[t]
        unsigned pack = (unsigned)f2bf(v0) | ((unsigned)f2bf(v1) << 16);
        int m = (b << 10) + tt0 + tr;
        ((unsigned*)a2)[(size_t)m * (K2 / 2) + dd0 + dc] = pack;
    }
}

// 128x128-tile bf16 MFMA GEMM, global_load_lds staging with XOR-8 chunk swizzle.
// LDS chunk (row, lc) holds global 8-elem chunk (row, lc ^ (row&7)) -> 0 bank conflicts.
__global__ __launch_bounds__(256)
void gemm_gates(const unsigned short* __restrict__ A, const unsigned short* __restrict__ Bt,
                const float* __restrict__ bias,
                float* __restrict__ zc, float* __restrict__ fh, unsigned short* __restrict__ og) {
    __shared__ __align__(16) unsigned short As[128 * 64];
    __shared__ __align__(16) unsigned short Bs2[128 * 64];
    int tid = threadIdx.x;
    int n0 = blockIdx.x << 7;   // 24 n-tiles
    int m0 = blockIdx.y << 7;   // 128 m-tiles
    int wave = tid >> 6, lane = tid & 63;
    int wm = wave & 1, wn = wave >> 1;     // 2x2 waves -> 64x64 each
    int lm = lane & 15, q = lane >> 4;

    int lrow = lane >> 3, lchunk = lane & 7;
    int gch  = lchunk ^ lrow;
    const unsigned short* Ag = A  + (size_t)(m0 + wave * 32 + lrow) * K2 + gch * 8;
    const unsigned short* Bg = Bt + (size_t)(n0 + wave * 32 + lrow) * K2 + gch * 8;

    f32x4 acc[4][4] = {};
    for (int kb = 0; kb < K2; kb += 64) {
        #pragma unroll
        for (int j = 0; j < 4; j++) {
            int rbase = wave * 32 + j * 8;
            GLOAD_LDS16(Ag + (size_t)j * 8 * K2 + kb, &As[rbase * 64]);
            GLOAD_LDS16(Bg + (size_t)j * 8 * K2 + kb, &Bs2[rbase * 64]);
        }
        __syncthreads();
        #pragma unroll
        for (int ks = 0; ks < 64; ks += 32) {
            bf16x8 af[4], bfr[4];
            int cs = ks >> 3;
            int sw = (lm & 7);
            #pragma unroll
            for (int i = 0; i < 4; i++)
                af[i] = *(bf16x8*)&As[(wm * 64 + i * 16 + lm) * 64 + (((cs + q) ^ sw) << 3)];
            #pragma unroll
            for (int j = 0; j < 4; j++)
                bfr[j] = *(bf16x8*)&Bs2[(wn * 64 + j * 16 + lm) * 64 + (((cs + q) ^ sw) << 3)];
            #pragma unroll
            for (int i = 0; i < 4; i++)
                #pragma unroll
                for (int j = 0; j < 4; j++)
                    acc[i][j] = __builtin_amdgcn_mfma_f32_16x16x32_bf16(af[i], bfr[j], acc[i][j], 0, 0, 0);
        }
        __syncthreads();
    }
    // Epilogue: C/D layout col=lane&15, row=(lane>>4)*4+reg
    int gt = n0 >> 10;   // 0:z(tanh)->zc  1:f(sigm)->fh  2:o(sigm)->og fp16
    #pragma unroll
    for (int i = 0; i < 4; i++) {
        int mrow = m0 + wm * 64 + i * 16 + q * 4;
        #pragma unroll
        for (int j = 0; j < 4; j++) {
            int n = n0 + wn * 64 + j * 16 + lm;
            float bv = bias[n];
            int hcol = n & 1023;
            #pragma unroll
            for (int r = 0; r < 4; r++) {
                float g = acc[i][j][r] + bv;
                size_t idx = (size_t)(mrow + r) * Hsz + hcol;
                if (gt == 0) {
                    float e = __expf(2.f * g);
                    zc[idx] = __fdividef(e - 1.f, e + 1.f);
                } else {
                    float s = __fdividef(1.f, 1.f + __expf(-g));
                    if (gt == 1) fh[idx] = s;
                    else         og[idx] = f2h(s);
                }
            }
        }
    }
}

// Single-pass fo-pooling scan with decoupled look-back.
// Block = (seq = b*2+hb covering 512 h, chunk ch of 32 t-steps), 2 chains/thread.
// pass A: read z,f once (keep packed fp16 in regs), build chunk affine (fp32).
// look-back: spin on predecessor's self-flagged 64-bit entries; publish own c_out.
// apply: recurrence from registers; zc <- c_seq, fh <- o*c (in-place, block-exclusive).
__global__ __launch_bounds__(256, 3)
void qrnn_scan(float* __restrict__ zc, float* __restrict__ fh,
               const unsigned short* __restrict__ og,
               unsigned long long* __restrict__ pub, int* __restrict__ ticket) {
    __shared__ int s_vb;
    if (threadIdx.x == 0) s_vb = atomicAdd(ticket, 1);
    __syncthreads();
    int v   = s_vb;
    int seq = v & (NSEQ - 1);          // ticket order: all chunks-ch of every seq
    int ch  = v >> 5;                  // before any chunk ch+1 -> no deadlock
    int b = seq >> 1, hb = seq & 1;
    int j2 = threadIdx.x * 2;          // position within 512-h slice
    int h  = hb * 512 + j2;
    size_t base = ((size_t)b << 20) + ((size_t)(ch * CL) << 10) + h;

    // ---- pass A: single read of z,f; affine accum in fp32; stash fp16-packed ----
    float ax = 1.f, ay = 1.f, bx = 0.f, by = 0.f;
    uint2 pk[CL];
    #pragma unroll
    for (int s = 0; s < CL; s++) {
        size_t idx = base + ((size_t)s << 10);
        float2 z = *(const float2*)&zc[idx];
        float2 f = *(const float2*)&fh[idx];
        ax *= f.x; bx = z.x + f.x * (bx - z.x);
        ay *= f.y; by = z.y + f.y * (by - z.y);
        pk[s].x = (unsigned)f2h(z.x) | ((unsigned)f2h(f.x) << 16);
        pk[s].y = (unsigned)f2h(z.y) | ((unsigned)f2h(f.y) << 16);
    }

    // ---- look-back: get chunk-entry state from predecessor ----
    float cx = 0.f, cy = 0.f;
    unsigned long long* slot = pub + ((size_t)seq * NCH + ch) * 512;
    if (ch > 0) {
        unsigned long long* ps = slot - 512;
        unsigned long long v0, v1;
        for (;;) {
            v0 = __hip_atomic_load(&ps[j2], __ATOMIC_RELAXED, __HIP_MEMORY_SCOPE_AGENT);
            if (v0 >> 32) break;
            __builtin_amdgcn_s_sleep(4);
        }
        for (;;) {
            v1 = __hip_atomic_load(&ps[j2 + 1], __ATOMIC_RELAXED, __HIP_MEMORY_SCOPE_AGENT);
            if (v1 >> 32) break;
            __builtin_amdgcn_s_sleep(4);
        }
        cx = __uint_as_float((unsigned)v0);
        cy = __uint_as_float((unsigned)v1);
    }
    if (ch < NCH - 1) {   // publish c_out = a*c_in + b (value+flag in one atomic word)
        unsigned long long px = (1ull << 32) | (unsigned long long)__float_as_uint(ax * cx + bx);
        unsigned long long py = (1ull << 32) | (unsigned long long)__float_as_uint(ay * cy + by);
        __hip_atomic_store(&slot[j2],     px, __ATOMIC_RELAXED, __HIP_MEMORY_SCOPE_AGENT);
        __hip_atomic_store(&slot[j2 + 1], py, __ATOMIC_RELAXED, __HIP_MEMORY_SCOPE_AGENT);
    }

    // ---- apply: recurrence from registers; write c and h = o*c ----
    #pragma unroll
    for (int s = 0; s < CL; s++) {
        size_t idx = base + ((size_t)s << 10);
        unsigned ov = *(const unsigned*)&og[idx];   // two fp16 o-gates
        float zx = h2f((unsigned short)(pk[s].x & 0xFFFF));
        float fx = h2f((unsigned short)(pk[s].x >> 16));
        float zy = h2f((unsigned short)(pk[s].y & 0xFFFF));
        float fy = h2f((unsigned short)(pk[s].y >> 16));
        cx = zx + fx * (cx - zx);
        cy = zy + fy * (cy - zy);
        *(float2*)&zc[idx] = make_float2(cx, cy);
        float ox = h2f((unsigned short)(ov & 0xFFFF));
        float oy = h2f((unsigned short)(ov >> 16));
        *(float2*)&fh[idx] = make_float2(ox * cx, oy * cy);
    }
}

extern "C" void kernel_launch(void* const* d_in, const int* in_sizes, int n_in,
                              void* d_out, int out_size, void* d_ws, size_t ws_size,
                              hipStream_t stream) {
    const float* x    = (const float*)d_in[0];   // [16,1024,1024]
    const float* w    = (const float*)d_in[1];   // [3072,1024,2]
    const float* bias = (const float*)d_in[2];   // [3072]
    float* zc = (float*)d_out;                               // c_seq out (holds z pre-scan)
    float* fh = (float*)d_out + (size_t)Mtot * Hsz;          // h_seq out (holds f pre-scan)
    unsigned short* a2 = (unsigned short*)d_ws;              // 64 MB
    unsigned short* wb = a2 + (size_t)Mtot * K2;             // 12.6 MB
    unsigned short* og = wb + (size_t)Ntot * K2;             // 32 MB (o gate, fp16)
    unsigned long long* pub = (unsigned long long*)(og + (size_t)Mtot * Hsz);  // 4 MB
    int* ticket = (int*)(pub + (size_t)NSEQ * NCH * 512);

    // neutralize the 0xAA ws poison on pub+ticket (poison has flag bits set)
    hipMemsetAsync(pub, 0, (size_t)NSEQ * NCH * 512 * 8 + 64, stream);
    hipLaunchKernelGGL(prep, dim3(5632), dim3(256), 0, stream, x, a2, w, wb);
    hipLaunchKernelGGL(gemm_gates, dim3(24, 128), dim3(256), 0, stream, a2, wb, bias, zc, fh, og);
    hipLaunchKernelGGL(qrnn_scan, dim3(Bsz * 2 * NCH), dim3(256), 0, stream, zc, fh, og, pub, ticket);
}